// Round 6
// baseline (247.118 us; speedup 1.0000x reference)
//
#include <hip/hip_runtime.h>
#include <hip/hip_fp16.h>
#include <math.h>

#define T_STEPS 12
#define HID 64
#define GWPB 7              // waves per block = 32-node tiles per block; 224 blocks
#define GBLOCK (GWPB*64)    // 448 threads
#define HSTR2 68            // h-tile row stride in u32 (64 + 4 pad)
#define B_LDS_BYTES 49152   // 48 slots x 512 fp16 (single-precision-B, fp16)
#define WG_LDS_BYTES 1792   // W_gcn(128) + b_gcn(64) + interleaved biases (256) = 448 f32
#define H_LDS_BYTES (GWPB*32*HSTR2*4)   // 60928: 32 rows per wave now
#define LDS_TOTAL (B_LDS_BYTES + WG_LDS_BYTES + H_LDS_BYTES)  // 111872

typedef _Float16 half8 __attribute__((ext_vector_type(8)));
typedef __fp16   fp16x2 __attribute__((ext_vector_type(2)));   // pkrtz result type
typedef __attribute__((ext_vector_type(4))) float floatx4;

__device__ __forceinline__ unsigned prm(unsigned a, unsigned b, unsigned s){
  return __builtin_amdgcn_perm(a, b, s);
}
// Fast transcendentals: without -ffast-math, 1.0f/x lowers to the full IEEE
// divide sequence (~10 serially-dependent VALU ops). v_rcp_f32 is ~1ulp.
__device__ __forceinline__ float fast_sigmoid(float x){
  float e = __builtin_amdgcn_exp2f(-1.442695041f * x);
  return __builtin_amdgcn_rcpf(1.0f + e);
}
__device__ __forceinline__ float fast_tanh(float x){   // tanh(x) = 1 - 2/(1+e^{2x})
  float e = __builtin_amdgcn_exp2f(2.885390082f * x);
  return fmaf(-2.0f, __builtin_amdgcn_rcpf(1.0f + e), 1.0f);
}
// split f32 pair -> fp16 hi pair + fp16 residual pair (RTZ hi, residual near-exact)
__device__ __forceinline__ void split2(float f0, float f1, unsigned &hi, unsigned &lo){
  fp16x2 h = __builtin_amdgcn_cvt_pkrtz(f0, f1);
  float b0 = (float)h[0], b1 = (float)h[1];
  fp16x2 l = __builtin_amdgcn_cvt_pkrtz(f0 - b0, f1 - b1);
  hi = __builtin_bit_cast(unsigned, h);
  lo = __builtin_bit_cast(unsigned, l);
}

// --- CSR build ----------------------------------------------------------
// count + rank + packB fused. The atomicAdd RETURN VALUE is the per-dst
// sequence number — storing it lets fill_kernel run with ZERO atomics.
__global__ void count_packB_kernel(const int* __restrict__ ei, int E, int* __restrict__ cnt,
                                   int* __restrict__ rank,
                                   const float* __restrict__ W_ih, const float* __restrict__ W_hh,
                                   unsigned short* __restrict__ Bpk){
  int tid = blockIdx.x*blockDim.x + threadIdx.x;
  if (tid < E) rank[tid] = atomicAdd(&cnt[ei[E + tid]], 1);
  if (tid < 48*512){
    int q = tid >> 9;
    int rr = tid & 511;
    int l = rr >> 3, j = rr & 7;
    int g, c4, kt;
    if (q < 32){ g = q >> 4; int rem = q & 15; c4 = rem >> 2; kt = rem & 3; }
    else if (q < 40){ g = 2; c4 = (q-32) >> 1; kt = (q-32) & 1; }
    else            { g = 3; c4 = (q-40) >> 1; kt = ((q-40) & 1) + 2; }
    int k  = kt*32 + (l >> 4)*8 + j;
    int n  = l & 15;
    int jc = c4*16 + n;
    float w;
    if (g == 0)      w = (k < 64) ? W_ih[jc*64 + k]      : W_hh[jc*64 + (k-64)];
    else if (g == 1) w = (k < 64) ? W_ih[(64+jc)*64 + k] : W_hh[(64+jc)*64 + (k-64)];
    else if (g == 2) w = W_ih[(128+jc)*64 + k];
    else             w = W_hh[(128+jc)*64 + (k-64)];
    _Float16 hv = (_Float16)w;   // RNE
    Bpk[q*512 + l*8 + j] = __builtin_bit_cast(unsigned short, hv);
  }
}

__global__ void dinv_scale_kernel(const int* __restrict__ cnt, const float* __restrict__ x,
                                  float* __restrict__ dinv, float4* __restrict__ xs, int N){
  int tid = blockIdx.x*blockDim.x + threadIdx.x;
  if (tid >= N*6) return;
  int n = tid / 6;
  float dn = rsqrtf((float)cnt[n] + 1.0f);
  if ((tid - n*6) == 0) dinv[n] = dn;
  float4 v = ((const float4*)x)[tid];
  xs[tid] = make_float4(dn*v.x, dn*v.y, dn*v.z, dn*v.w);
}

// per-1024-block inclusive scan: wave shfl-scan + cross-wave fixup (2 barriers)
__global__ void scan1_kernel(const int* __restrict__ cnt, int* __restrict__ part,
                             int* __restrict__ bsum, int N){
  __shared__ int wsum[16];
  int tid = threadIdx.x;
  int g = blockIdx.x*1024 + tid;
  int v = (g < N) ? cnt[g] : 0;
  int lane = tid & 63, wv = tid >> 6;
  int s = v;
  #pragma unroll
  for (int off = 1; off < 64; off <<= 1){
    int u = __shfl_up(s, off, 64);
    if (lane >= off) s += u;
  }
  if (lane == 63) wsum[wv] = s;
  __syncthreads();
  if (wv == 0){
    int w = (lane < 16) ? wsum[lane] : 0;
    #pragma unroll
    for (int off = 1; off < 16; off <<= 1){
      int u = __shfl_up(w, off, 64);
      if (lane >= off) w += u;
    }
    if (lane < 16) wsum[lane] = w;
  }
  __syncthreads();
  int incl = (wv ? wsum[wv-1] : 0) + s;
  if (g < N) part[g] = incl;
  if (tid == 1023) bsum[blockIdx.x] = incl;
}

// scan3 with scan2 inlined: each block redundantly scans the <=64 block-sums
__global__ void scan3_kernel(const int* __restrict__ part, const int* __restrict__ bsum,
                             const int* __restrict__ cnt, int* __restrict__ row_start,
                             int N, int nb){
  __shared__ int sb[64];
  if (threadIdx.x < 64){
    int v = (threadIdx.x < nb) ? bsum[threadIdx.x] : 0;
    #pragma unroll
    for (int off = 1; off < 64; off <<= 1){
      int u = __shfl_up(v, off, 64);
      if ((int)(threadIdx.x & 63) >= off) v += u;
    }
    sb[threadIdx.x] = v;
  }
  __syncthreads();
  int g = blockIdx.x*blockDim.x + threadIdx.x;
  if (g < N){
    int b = g >> 10;
    int incl = part[g] + (b ? sb[b-1] : 0);
    row_start[g] = incl - cnt[g];
    if (g == N-1) row_start[N] = incl;
  }
}

// atomic-free fill: position = row_start[dst] + rank[e] (rank from count pass)
__global__ void fill_kernel(const int* __restrict__ ei, int E,
                            const int* __restrict__ row_start,
                            const int* __restrict__ rank, int* __restrict__ csr){
  int e = blockIdx.x*blockDim.x + threadIdx.x;
  if (e < E){
    int dst = ei[E + e];
    csr[row_start[dst] + rank[e]] = ei[e];  // src
  }
}

__global__ void gather6_kernel(const float4* __restrict__ xs, const int* __restrict__ row_start,
                               const int* __restrict__ csr, const float* __restrict__ dinv,
                               float4* __restrict__ rin, int N){
  int tid = blockIdx.x*blockDim.x + threadIdx.x;
  if (tid >= N*6) return;
  int n = tid / 6;
  int q = tid - n*6;
  int s0 = row_start[n], s1 = row_start[n+1];
  float4 acc = xs[n*6 + q];          // self term
  int e = s0;
  for (; e + 1 < s1; e += 2){
    int sa = csr[e], sb = csr[e+1];
    float4 va = xs[sa*6 + q];
    float4 vb = xs[sb*6 + q];
    acc.x += va.x + vb.x;
    acc.y += va.y + vb.y;
    acc.z += va.z + vb.z;
    acc.w += va.w + vb.w;
  }
  if (e < s1){
    float4 va = xs[csr[e]*6 + q];
    acc.x += va.x; acc.y += va.y; acc.z += va.z; acc.w += va.w;
  }
  float dn = dinv[n];
  rin[tid] = make_float4(dn*acc.x, dn*acc.y, dn*acc.z, dn*acc.w);
}

// Fused 12-step GRU + FC via fp16 2-term MFMA (Ahi*B + Alo*B; B single fp16).
// THIS ROUND: wave = 32 nodes (two 16-row M-tiles, same proven 16x16x32
// fragment layout). Each B-fragment LDS read now feeds 4 MFMAs (2 M-tiles x
// hi/lo) instead of 2 — per-node LDS-pipe cost halves (LDS was the dominant
// pipe: ~60us of the 96us wall; model says ~40us now). 7 waves/block, 224
// blocks, 1/CU. Wave-count cap is 2 waves/SIMD, so the VGPR budget is 256 —
// the doubled A-frags (+32) and 8 live accumulators fit without spilling
// (waves_per_eu(1,2) signals the 256-VGPR budget).
__global__ __attribute__((amdgpu_waves_per_eu(1, 2))) __launch_bounds__(GBLOCK)
void gru16_kernel(const float* __restrict__ rin,
                  const float* __restrict__ W_gcn, const float* __restrict__ b_gcn,
                  const unsigned short* __restrict__ Bpk,
                  const float* __restrict__ b_ih, const float* __restrict__ b_hh,
                  const float* __restrict__ W_fc, const float* __restrict__ b_fc,
                  float* __restrict__ out, int N, int ntiles){
  extern __shared__ char smem[];
  unsigned short* Bl = (unsigned short*)smem;
  float*    wgl = (float*)(smem + B_LDS_BYTES);
  unsigned* hl  = (unsigned*)(smem + B_LDS_BYTES + WG_LDS_BYTES);

  {
    const int4* Bg = (const int4*)Bpk;
    int4* Bd = (int4*)smem;
    for (int i = threadIdx.x; i < 3072; i += GBLOCK) Bd[i] = Bg[i];
    if (threadIdx.x < 64){
      int l = threadIdx.x;
      wgl[l]       = W_gcn[l];
      wgl[64 + l]  = W_gcn[64 + l];
      wgl[128 + l] = b_gcn[l];
      wgl[192 + 4*l + 0] = b_ih[l]       + b_hh[l];        // bR
      wgl[192 + 4*l + 1] = b_ih[64 + l]  + b_hh[64 + l];   // bZ
      wgl[192 + 4*l + 2] = b_ih[128 + l];                  // bNi
      wgl[192 + 4*l + 3] = b_hh[128 + l];                  // bNh
    }
  }
  __syncthreads();

  int lane = threadIdx.x & 63;
  int wid  = threadIdx.x >> 6;
  int tile = blockIdx.x*GWPB + wid;
  if (tile >= ntiles) return;
  int n0   = tile << 5;               // 32 nodes per tile
  int quad = lane >> 4;
  int n16  = lane & 15;
  unsigned* hwp = hl + wid*(32*HSTR2);

  for (int i = lane; i < 32*HSTR2; i += 64) hwp[i] = 0u;   // wave-private, no barrier

  float wfc = W_fc[lane], bfc = b_fc[0];

  int nn  = n0 + n16;      if (nn  > N-1) nn  = N-1;   // M0 node
  int nn2 = n0 + 16 + n16; if (nn2 > N-1) nn2 = N-1;   // M1 node
  const float* rbase  = rin + (size_t)nn*24;
  const float* rbase2 = rin + (size_t)nn2*24;
  float2 rcur  = *(const float2*)rbase;
  float2 rcur2 = *(const float2*)rbase2;

  #pragma unroll 1
  for (int t = 0; t < T_STEPS; ++t){
    float2 rnx  = (t < T_STEPS-1) ? *(const float2*)(rbase  + 2*(t+1)) : rcur;
    float2 rnx2 = (t < T_STEPS-1) ? *(const float2*)(rbase2 + 2*(t+1)) : rcur2;

    half8 ahi0[4], alo0[4], ahi1[4], alo1[4];
    // s half (kt 0,1): A-frag from wgl; wgl loads SHARED by both M-tiles
    #pragma unroll
    for (int kt = 0; kt < 2; ++kt){
      int j0 = kt*32 + quad*8;
      floatx4 g0a = *(floatx4*)&wgl[j0],       g0b = *(floatx4*)&wgl[j0+4];
      floatx4 g1a = *(floatx4*)&wgl[64 + j0],  g1b = *(floatx4*)&wgl[64 + j0+4];
      floatx4 bga = *(floatx4*)&wgl[128 + j0], bgb = *(floatx4*)&wgl[128 + j0+4];
      float f0[8], f1[8];
      #pragma unroll
      for (int j = 0; j < 4; ++j){
        f0[j]   = fmaxf(fmaf(rcur.x,  g0a[j], fmaf(rcur.y,  g1a[j], bga[j])), 0.f);
        f0[4+j] = fmaxf(fmaf(rcur.x,  g0b[j], fmaf(rcur.y,  g1b[j], bgb[j])), 0.f);
        f1[j]   = fmaxf(fmaf(rcur2.x, g0a[j], fmaf(rcur2.y, g1a[j], bga[j])), 0.f);
        f1[4+j] = fmaxf(fmaf(rcur2.x, g0b[j], fmaf(rcur2.y, g1b[j], bgb[j])), 0.f);
      }
      union { half8 v; unsigned w[4]; } H0, L0, H1, L1;
      #pragma unroll
      for (int p2 = 0; p2 < 4; ++p2){
        split2(f0[2*p2], f0[2*p2+1], H0.w[p2], L0.w[p2]);
        split2(f1[2*p2], f1[2*p2+1], H1.w[p2], L1.w[p2]);
      }
      ahi0[kt] = H0.v; alo0[kt] = L0.v;
      ahi1[kt] = H1.v; alo1[kt] = L1.v;
    }
    // h half (kt 2,3): packed u32 (hi low16, lo high16), 1 perm/element
    #pragma unroll
    for (int kt = 2; kt < 4; ++kt){
      int base0 = n16*HSTR2       + (kt-2)*32 + quad*8;
      int base1 = (16+n16)*HSTR2  + (kt-2)*32 + quad*8;
      uint4 wa = *(const uint4*)&hwp[base0];
      uint4 wb = *(const uint4*)&hwp[base0+4];
      uint4 wc = *(const uint4*)&hwp[base1];
      uint4 wd = *(const uint4*)&hwp[base1+4];
      union { half8 v; unsigned w[4]; } H0, L0, H1, L1;
      H0.w[0] = prm(wa.y, wa.x, 0x05040100u); L0.w[0] = prm(wa.y, wa.x, 0x07060302u);
      H0.w[1] = prm(wa.w, wa.z, 0x05040100u); L0.w[1] = prm(wa.w, wa.z, 0x07060302u);
      H0.w[2] = prm(wb.y, wb.x, 0x05040100u); L0.w[2] = prm(wb.y, wb.x, 0x07060302u);
      H0.w[3] = prm(wb.w, wb.z, 0x05040100u); L0.w[3] = prm(wb.w, wb.z, 0x07060302u);
      H1.w[0] = prm(wc.y, wc.x, 0x05040100u); L1.w[0] = prm(wc.y, wc.x, 0x07060302u);
      H1.w[1] = prm(wc.w, wc.z, 0x05040100u); L1.w[1] = prm(wc.w, wc.z, 0x07060302u);
      H1.w[2] = prm(wd.y, wd.x, 0x05040100u); L1.w[2] = prm(wd.y, wd.x, 0x07060302u);
      H1.w[3] = prm(wd.w, wd.z, 0x05040100u); L1.w[3] = prm(wd.w, wd.z, 0x07060302u);
      ahi0[kt] = H0.v; alo0[kt] = L0.v;
      ahi1[kt] = H1.v; alo1[kt] = L1.v;
    }

    // unroll-2 on c4: two gate-groups in flight (epilogue ∥ next LDS/MFMA).
    #pragma unroll 2
    for (int c4 = 0; c4 < 4; ++c4){
      int jc = (c4<<4) + n16;
      floatx4 bv = *(floatx4*)&wgl[192 + 4*jc];     // bR,bZ,bNi,bNh in one b128
      // hprev prefetch before the MFMA cluster (latency hides under MFMAs)
      unsigned hpw0[4], hpw1[4];
      #pragma unroll
      for (int r = 0; r < 4; ++r){
        hpw0[r] = hwp[(quad*4 + r)*HSTR2      + (c4<<4) + n16];
        hpw1[r] = hwp[(16 + quad*4 + r)*HSTR2 + (c4<<4) + n16];
      }
      floatx4 aR0 = (floatx4){bv[0], bv[0], bv[0], bv[0]}, aR1 = aR0;
      floatx4 aZ0 = (floatx4){bv[1], bv[1], bv[1], bv[1]}, aZ1 = aZ0;
      floatx4 aN0 = (floatx4){bv[2], bv[2], bv[2], bv[2]}, aN1 = aN0;
      floatx4 aH0 = (floatx4){bv[3], bv[3], bv[3], bv[3]}, aH1 = aH0;
      #pragma unroll
      for (int kt = 0; kt < 4; ++kt){
        int qr = (c4<<2) + kt;
        half8 wR = *(const half8*)&Bl[qr*512 + lane*8];
        aR0 = __builtin_amdgcn_mfma_f32_16x16x32_f16(ahi0[kt], wR, aR0, 0,0,0);
        aR0 = __builtin_amdgcn_mfma_f32_16x16x32_f16(alo0[kt], wR, aR0, 0,0,0);
        aR1 = __builtin_amdgcn_mfma_f32_16x16x32_f16(ahi1[kt], wR, aR1, 0,0,0);
        aR1 = __builtin_amdgcn_mfma_f32_16x16x32_f16(alo1[kt], wR, aR1, 0,0,0);
        int qz = 16 + (c4<<2) + kt;
        half8 wZ = *(const half8*)&Bl[qz*512 + lane*8];
        aZ0 = __builtin_amdgcn_mfma_f32_16x16x32_f16(ahi0[kt], wZ, aZ0, 0,0,0);
        aZ0 = __builtin_amdgcn_mfma_f32_16x16x32_f16(alo0[kt], wZ, aZ0, 0,0,0);
        aZ1 = __builtin_amdgcn_mfma_f32_16x16x32_f16(ahi1[kt], wZ, aZ1, 0,0,0);
        aZ1 = __builtin_amdgcn_mfma_f32_16x16x32_f16(alo1[kt], wZ, aZ1, 0,0,0);
        if (kt < 2){
          int qn = 32 + (c4<<1) + kt;
          half8 wN = *(const half8*)&Bl[qn*512 + lane*8];
          aN0 = __builtin_amdgcn_mfma_f32_16x16x32_f16(ahi0[kt], wN, aN0, 0,0,0);
          aN0 = __builtin_amdgcn_mfma_f32_16x16x32_f16(alo0[kt], wN, aN0, 0,0,0);
          aN1 = __builtin_amdgcn_mfma_f32_16x16x32_f16(ahi1[kt], wN, aN1, 0,0,0);
          aN1 = __builtin_amdgcn_mfma_f32_16x16x32_f16(alo1[kt], wN, aN1, 0,0,0);
        } else {
          int qh = 40 + (c4<<1) + (kt-2);
          half8 wH = *(const half8*)&Bl[qh*512 + lane*8];
          aH0 = __builtin_amdgcn_mfma_f32_16x16x32_f16(ahi0[kt], wH, aH0, 0,0,0);
          aH0 = __builtin_amdgcn_mfma_f32_16x16x32_f16(alo0[kt], wH, aH0, 0,0,0);
          aH1 = __builtin_amdgcn_mfma_f32_16x16x32_f16(ahi1[kt], wH, aH1, 0,0,0);
          aH1 = __builtin_amdgcn_mfma_f32_16x16x32_f16(alo1[kt], wH, aH1, 0,0,0);
        }
      }
      // epilogue M0: rows quad*4+r; M1: rows 16+quad*4+r; col = c4*16+n16
      #pragma unroll
      for (int r = 0; r < 4; ++r){
        fp16x2 hp2 = __builtin_bit_cast(fp16x2, hpw0[r]);
        float hprev = (float)hp2[0] + (float)hp2[1];
        float rg = fast_sigmoid(aR0[r]);
        float zg = fast_sigmoid(aZ0[r]);
        float ng = fast_tanh(fmaf(rg, aH0[r], aN0[r]));
        float hn = fmaf(zg, hprev - ng, ng);
        fp16x2 t0 = __builtin_amdgcn_cvt_pkrtz(hn, hn);
        float back = (float)t0[0];
        fp16x2 pw = __builtin_amdgcn_cvt_pkrtz(hn, hn - back);
        hwp[(quad*4 + r)*HSTR2 + (c4<<4) + n16] = __builtin_bit_cast(unsigned, pw);
      }
      #pragma unroll
      for (int r = 0; r < 4; ++r){
        fp16x2 hp2 = __builtin_bit_cast(fp16x2, hpw1[r]);
        float hprev = (float)hp2[0] + (float)hp2[1];
        float rg = fast_sigmoid(aR1[r]);
        float zg = fast_sigmoid(aZ1[r]);
        float ng = fast_tanh(fmaf(rg, aH1[r], aN1[r]));
        float hn = fmaf(zg, hprev - ng, ng);
        fp16x2 t0 = __builtin_amdgcn_cvt_pkrtz(hn, hn);
        float back = (float)t0[0];
        fp16x2 pw = __builtin_amdgcn_cvt_pkrtz(hn, hn - back);
        hwp[(16 + quad*4 + r)*HSTR2 + (c4<<4) + n16] = __builtin_bit_cast(unsigned, pw);
      }
    }
    rcur = rnx; rcur2 = rnx2;
  }

  // FC epilogue: reconstruct h = hi + lo (32 rows)
  #pragma unroll 1
  for (int m = 0; m < 32; ++m){
    fp16x2 hw2 = __builtin_bit_cast(fp16x2, hwp[m*HSTR2 + lane]);
    float hv = (float)hw2[0] + (float)hw2[1];
    float v = hv * wfc;
    #pragma unroll
    for (int off = 32; off >= 1; off >>= 1) v += __shfl_xor(v, off, 64);
    int n = n0 + m;
    if (lane == 0 && n < N) out[n] = v + bfc;
  }
}

extern "C" void kernel_launch(void* const* d_in, const int* in_sizes, int n_in,
                              void* d_out, int out_size, void* d_ws, size_t ws_size,
                              hipStream_t stream){
  const float* x     = (const float*)d_in[0];
  const int*   ei    = (const int*)d_in[1];
  const float* W_gcn = (const float*)d_in[2];
  const float* b_gcn = (const float*)d_in[3];
  const float* W_ih  = (const float*)d_in[4];
  const float* W_hh  = (const float*)d_in[5];
  const float* b_ih  = (const float*)d_in[6];
  const float* b_hh  = (const float*)d_in[7];
  const float* W_fc  = (const float*)d_in[8];
  const float* b_fc  = (const float*)d_in[9];
  float* out = (float*)d_out;
  const int N = in_sizes[0] / (T_STEPS*2);
  const int E = in_sizes[1] / 2;
  const int NB1024 = (N + 1023) / 1024;

  char* p = (char*)d_ws;
  auto alloc = [&](size_t bytes)->char*{
    char* r = p; p += (bytes + 255) & ~(size_t)255; return r;
  };
  int*   cnt       = (int*)  alloc((size_t)N*4);
  int*   row_start = (int*)  alloc((size_t)(N+1)*4);
  int*   rank      = (int*)  alloc((size_t)E*4);
  int*   csr       = (int*)  alloc((size_t)E*4);
  float* dinv      = (float*)alloc((size_t)N*4);
  int*   part      = (int*)  alloc((size_t)N*4);
  int*   bsum      = (int*)  alloc((size_t)NB1024*4);
  float* rin       = (float*)alloc((size_t)N*24*4);
  float* xs        = (float*)alloc((size_t)N*24*4);
  unsigned short* Bpk = (unsigned short*)alloc((size_t)24576*2);

  hipMemsetAsync(cnt, 0, (size_t)N*4, stream);
  {
    int work = (E > 48*512) ? E : 48*512;
    count_packB_kernel<<<(work+255)/256, 256, 0, stream>>>(ei, E, cnt, rank, W_ih, W_hh, Bpk);
  }
  dinv_scale_kernel<<<(N*6+255)/256, 256, 0, stream>>>(cnt, x, dinv, (float4*)xs, N);
  scan1_kernel<<<NB1024, 1024, 0, stream>>>(cnt, part, bsum, N);
  scan3_kernel<<<(N+255)/256, 256, 0, stream>>>(part, bsum, cnt, row_start, N, NB1024);
  fill_kernel<<<(E+255)/256, 256, 0, stream>>>(ei, E, row_start, rank, csr);
  gather6_kernel<<<(N*6+255)/256, 256, 0, stream>>>((const float4*)xs, row_start, csr,
                                                    dinv, (float4*)rin, N);

  (void)hipFuncSetAttribute((const void*)gru16_kernel,
                            hipFuncAttributeMaxDynamicSharedMemorySize, LDS_TOTAL);
  int ntiles = (N + 31) / 32;                      // 1563 (32-node tiles)
  int blocks = (ntiles + GWPB - 1) / GWPB;         // 224
  gru16_kernel<<<blocks, GBLOCK, LDS_TOTAL, stream>>>(rin, W_gcn, b_gcn, Bpk,
                                                      b_ih, b_hh, W_fc, b_fc,
                                                      out, N, ntiles);
}

// Round 7
// 239.218 us; speedup vs baseline: 1.0330x; 1.0330x over previous
//
#include <hip/hip_runtime.h>
#include <hip/hip_fp16.h>
#include <math.h>

#define T_STEPS 12
#define HID 64
#define GWPB 13             // waves per block (241 blocks <= 256 CUs, all resident)
#define GBLOCK (GWPB*64)    // 832 threads
#define HSTR2 68            // h-tile row stride in u32 (64 + 4 pad)
#define B_LDS_BYTES 49152   // 48 slots x 512 fp16 (single-precision-B, fp16)
#define WG_LDS_BYTES 1792   // W_gcn(128) + b_gcn(64) + interleaved biases (256) = 448 f32
#define H_LDS_BYTES (GWPB*16*HSTR2*4)   // 56576
#define LDS_TOTAL (B_LDS_BYTES + WG_LDS_BYTES + H_LDS_BYTES)  // 107520

typedef _Float16 half8 __attribute__((ext_vector_type(8)));
typedef __fp16   fp16x2 __attribute__((ext_vector_type(2)));   // pkrtz result type
typedef __attribute__((ext_vector_type(4))) float floatx4;

__device__ __forceinline__ unsigned prm(unsigned a, unsigned b, unsigned s){
  return __builtin_amdgcn_perm(a, b, s);
}
// Fast transcendentals: without -ffast-math, 1.0f/x lowers to the full IEEE
// divide sequence (~10 serially-dependent VALU ops). v_rcp_f32 is ~1ulp.
__device__ __forceinline__ float fast_sigmoid(float x){
  float e = __builtin_amdgcn_exp2f(-1.442695041f * x);
  return __builtin_amdgcn_rcpf(1.0f + e);
}
__device__ __forceinline__ float fast_tanh(float x){   // tanh(x) = 1 - 2/(1+e^{2x})
  float e = __builtin_amdgcn_exp2f(2.885390082f * x);
  return fmaf(-2.0f, __builtin_amdgcn_rcpf(1.0f + e), 1.0f);
}
// split f32 pair -> fp16 hi pair + fp16 residual pair (RTZ hi, residual near-exact)
__device__ __forceinline__ void split2(float f0, float f1, unsigned &hi, unsigned &lo){
  fp16x2 h = __builtin_amdgcn_cvt_pkrtz(f0, f1);
  float b0 = (float)h[0], b1 = (float)h[1];
  fp16x2 l = __builtin_amdgcn_cvt_pkrtz(f0 - b0, f1 - b1);
  hi = __builtin_bit_cast(unsigned, h);
  lo = __builtin_bit_cast(unsigned, l);
}

// --- CSR build ----------------------------------------------------------
// count + rank + packB fused. The atomicAdd RETURN VALUE is the per-dst
// sequence number — storing it lets fill_kernel run with ZERO atomics.
__global__ void count_packB_kernel(const int* __restrict__ ei, int E, int* __restrict__ cnt,
                                   int* __restrict__ rank,
                                   const float* __restrict__ W_ih, const float* __restrict__ W_hh,
                                   unsigned short* __restrict__ Bpk){
  int tid = blockIdx.x*blockDim.x + threadIdx.x;
  if (tid < E) rank[tid] = atomicAdd(&cnt[ei[E + tid]], 1);
  if (tid < 48*512){
    int q = tid >> 9;
    int rr = tid & 511;
    int l = rr >> 3, j = rr & 7;
    int g, c4, kt;
    if (q < 32){ g = q >> 4; int rem = q & 15; c4 = rem >> 2; kt = rem & 3; }
    else if (q < 40){ g = 2; c4 = (q-32) >> 1; kt = (q-32) & 1; }
    else            { g = 3; c4 = (q-40) >> 1; kt = ((q-40) & 1) + 2; }
    int k  = kt*32 + (l >> 4)*8 + j;
    int n  = l & 15;
    int jc = c4*16 + n;
    float w;
    if (g == 0)      w = (k < 64) ? W_ih[jc*64 + k]      : W_hh[jc*64 + (k-64)];
    else if (g == 1) w = (k < 64) ? W_ih[(64+jc)*64 + k] : W_hh[(64+jc)*64 + (k-64)];
    else if (g == 2) w = W_ih[(128+jc)*64 + k];
    else             w = W_hh[(128+jc)*64 + (k-64)];
    _Float16 hv = (_Float16)w;   // RNE
    Bpk[q*512 + l*8 + j] = __builtin_bit_cast(unsigned short, hv);
  }
}

// per-1024-block inclusive scan: wave shfl-scan + cross-wave fixup (2 barriers)
__global__ void scan1_kernel(const int* __restrict__ cnt, int* __restrict__ part,
                             int* __restrict__ bsum, int N){
  __shared__ int wsum[16];
  int tid = threadIdx.x;
  int g = blockIdx.x*1024 + tid;
  int v = (g < N) ? cnt[g] : 0;
  int lane = tid & 63, wv = tid >> 6;
  int s = v;
  #pragma unroll
  for (int off = 1; off < 64; off <<= 1){
    int u = __shfl_up(s, off, 64);
    if (lane >= off) s += u;
  }
  if (lane == 63) wsum[wv] = s;
  __syncthreads();
  if (wv == 0){
    int w = (lane < 16) ? wsum[lane] : 0;
    #pragma unroll
    for (int off = 1; off < 16; off <<= 1){
      int u = __shfl_up(w, off, 64);
      if (lane >= off) w += u;
    }
    if (lane < 16) wsum[lane] = w;
  }
  __syncthreads();
  int incl = (wv ? wsum[wv-1] : 0) + s;
  if (g < N) part[g] = incl;
  if (tid == 1023) bsum[blockIdx.x] = incl;
}

// scan3 with scan2 inlined + dinv_scale fused (scan3 already reads cnt[g]
// per node; adding the dinv/xs writes here deletes a dispatch + a cnt pass).
__global__ void scan3_kernel(const int* __restrict__ part, const int* __restrict__ bsum,
                             const int* __restrict__ cnt, int* __restrict__ row_start,
                             const float* __restrict__ x, float* __restrict__ dinv,
                             float4* __restrict__ xs, int N, int nb){
  __shared__ int sb[64];
  if (threadIdx.x < 64){
    int v = (threadIdx.x < nb) ? bsum[threadIdx.x] : 0;
    #pragma unroll
    for (int off = 1; off < 64; off <<= 1){
      int u = __shfl_up(v, off, 64);
      if ((int)(threadIdx.x & 63) >= off) v += u;
    }
    sb[threadIdx.x] = v;
  }
  __syncthreads();
  int g = blockIdx.x*blockDim.x + threadIdx.x;
  if (g < N){
    int c = cnt[g];
    int b = g >> 10;
    int incl = part[g] + (b ? sb[b-1] : 0);
    row_start[g] = incl - c;
    if (g == N-1) row_start[N] = incl;
    float dn = rsqrtf((float)c + 1.0f);
    dinv[g] = dn;
    const float4* xg = (const float4*)x + (size_t)g*6;
    float4* xo = xs + (size_t)g*6;
    #pragma unroll
    for (int q = 0; q < 6; ++q){
      float4 v4 = xg[q];
      xo[q] = make_float4(dn*v4.x, dn*v4.y, dn*v4.z, dn*v4.w);
    }
  }
}

// atomic-free fill: position = row_start[dst] + rank[e] (rank from count pass)
__global__ void fill_kernel(const int* __restrict__ ei, int E,
                            const int* __restrict__ row_start,
                            const int* __restrict__ rank, int* __restrict__ csr){
  int e = blockIdx.x*blockDim.x + threadIdx.x;
  if (e < E){
    int dst = ei[E + e];
    csr[row_start[dst] + rank[e]] = ei[e];  // src
  }
}

__global__ void gather6_kernel(const float4* __restrict__ xs, const int* __restrict__ row_start,
                               const int* __restrict__ csr, const float* __restrict__ dinv,
                               float4* __restrict__ rin, int N){
  int tid = blockIdx.x*blockDim.x + threadIdx.x;
  if (tid >= N*6) return;
  int n = tid / 6;
  int q = tid - n*6;
  int s0 = row_start[n], s1 = row_start[n+1];
  float4 acc = xs[n*6 + q];          // self term
  int e = s0;
  for (; e + 1 < s1; e += 2){
    int sa = csr[e], sb = csr[e+1];
    float4 va = xs[sa*6 + q];
    float4 vb = xs[sb*6 + q];
    acc.x += va.x + vb.x;
    acc.y += va.y + vb.y;
    acc.z += va.z + vb.z;
    acc.w += va.w + vb.w;
  }
  if (e < s1){
    float4 va = xs[csr[e]*6 + q];
    acc.x += va.x; acc.y += va.y; acc.z += va.z; acc.w += va.w;
  }
  float dn = dinv[n];
  rin[tid] = make_float4(dn*acc.x, dn*acc.y, dn*acc.z, dn*acc.w);
}

// Fused 12-step GRU + FC via fp16 2-term MFMA (Ahi*B + Alo*B; B single fp16).
// Wave-private: wave = 16 nodes, owns all 64 channels, NO barriers in t-loop.
// 13 waves/block, 241 blocks (proven config: 32-node/7-wave variant regressed
// — kernel is latency-bound, wave count is the hiding resource).
// THIS ROUND: the 12 ds_read_b128 of W_gcn/b_gcn per t-step are t-INVARIANT —
// hoisted into registers (statically indexed via the unrolled kt loop).
// Removes ~18% of LDS ops and a serial LDS-latency link from every t-step's
// fragment-build critical path. +48 VGPR (~100 total, under the 128 cap of a
// 13-wave block's 4-wave SIMD).
__global__ __attribute__((amdgpu_waves_per_eu(1, 4))) __launch_bounds__(GBLOCK)
void gru16_kernel(const float* __restrict__ rin,
                  const float* __restrict__ W_gcn, const float* __restrict__ b_gcn,
                  const unsigned short* __restrict__ Bpk,
                  const float* __restrict__ b_ih, const float* __restrict__ b_hh,
                  const float* __restrict__ W_fc, const float* __restrict__ b_fc,
                  float* __restrict__ out, int N, int ntiles){
  extern __shared__ char smem[];
  unsigned short* Bl = (unsigned short*)smem;
  float*    wgl = (float*)(smem + B_LDS_BYTES);
  unsigned* hl  = (unsigned*)(smem + B_LDS_BYTES + WG_LDS_BYTES);

  {
    const int4* Bg = (const int4*)Bpk;
    int4* Bd = (int4*)smem;
    for (int i = threadIdx.x; i < 3072; i += GBLOCK) Bd[i] = Bg[i];
    if (threadIdx.x < 64){
      int l = threadIdx.x;
      wgl[l]       = W_gcn[l];
      wgl[64 + l]  = W_gcn[64 + l];
      wgl[128 + l] = b_gcn[l];
      // interleaved per-channel biases: one b128 read per c4 in the hot loop
      wgl[192 + 4*l + 0] = b_ih[l]       + b_hh[l];        // bR
      wgl[192 + 4*l + 1] = b_ih[64 + l]  + b_hh[64 + l];   // bZ
      wgl[192 + 4*l + 2] = b_ih[128 + l];                  // bNi
      wgl[192 + 4*l + 3] = b_hh[128 + l];                  // bNh
    }
  }
  __syncthreads();

  int lane = threadIdx.x & 63;
  int wid  = threadIdx.x >> 6;
  int tile = blockIdx.x*GWPB + wid;
  if (tile >= ntiles) return;
  int n0   = tile << 4;
  int quad = lane >> 4;
  int n16  = lane & 15;
  unsigned* hwp = hl + wid*(16*HSTR2);

  for (int i = lane; i < 16*HSTR2; i += 64) hwp[i] = 0u;   // wave-private, no barrier

  float wfc = W_fc[lane], bfc = b_fc[0];

  // t-invariant W_gcn/b_gcn A-side constants -> registers (static kt index)
  floatx4 G0a[2], G0b[2], G1a[2], G1b[2], Bga[2], Bgb[2];
  #pragma unroll
  for (int kt = 0; kt < 2; ++kt){
    int j0 = kt*32 + quad*8;
    G0a[kt] = *(floatx4*)&wgl[j0];        G0b[kt] = *(floatx4*)&wgl[j0+4];
    G1a[kt] = *(floatx4*)&wgl[64 + j0];   G1b[kt] = *(floatx4*)&wgl[64 + j0+4];
    Bga[kt] = *(floatx4*)&wgl[128 + j0];  Bgb[kt] = *(floatx4*)&wgl[128 + j0+4];
  }

  int nn = n0 + n16; if (nn > N-1) nn = N-1;
  const float* rbase = rin + (size_t)nn*24;
  float2 rcur = *(const float2*)rbase;

  #pragma unroll 1
  for (int t = 0; t < T_STEPS; ++t){
    float2 rnx = (t < T_STEPS-1) ? *(const float2*)(rbase + 2*(t+1)) : rcur;

    half8 ahi[4], alo[4];
    // s half (kt 0,1): A-frag from hoisted registers, fp16 split
    #pragma unroll
    for (int kt = 0; kt < 2; ++kt){
      float f[8];
      #pragma unroll
      for (int j = 0; j < 4; ++j){
        f[j]   = fmaxf(fmaf(rcur.x, G0a[kt][j], fmaf(rcur.y, G1a[kt][j], Bga[kt][j])), 0.f);
        f[4+j] = fmaxf(fmaf(rcur.x, G0b[kt][j], fmaf(rcur.y, G1b[kt][j], Bgb[kt][j])), 0.f);
      }
      union { half8 v; unsigned w[4]; } H, L;
      #pragma unroll
      for (int p2 = 0; p2 < 4; ++p2)
        split2(f[2*p2], f[2*p2+1], H.w[p2], L.w[p2]);
      ahi[kt] = H.v; alo[kt] = L.v;
    }
    // h half (kt 2,3): packed u32 (hi low16, lo high16), 1 perm/element
    #pragma unroll
    for (int kt = 2; kt < 4; ++kt){
      int base = n16*HSTR2 + (kt-2)*32 + quad*8;
      uint4 wa = *(const uint4*)&hwp[base];
      uint4 wb = *(const uint4*)&hwp[base+4];
      union { half8 v; unsigned w[4]; } H, L;
      H.w[0] = prm(wa.y, wa.x, 0x05040100u); L.w[0] = prm(wa.y, wa.x, 0x07060302u);
      H.w[1] = prm(wa.w, wa.z, 0x05040100u); L.w[1] = prm(wa.w, wa.z, 0x07060302u);
      H.w[2] = prm(wb.y, wb.x, 0x05040100u); L.w[2] = prm(wb.y, wb.x, 0x07060302u);
      H.w[3] = prm(wb.w, wb.z, 0x05040100u); L.w[3] = prm(wb.w, wb.z, 0x07060302u);
      ahi[kt] = H.v; alo[kt] = L.v;
    }

    // unroll-2: two gate-groups in flight (epilogue ∥ next LDS/MFMA).
    #pragma unroll 2
    for (int c4 = 0; c4 < 4; ++c4){
      int jc = (c4<<4) + n16;
      floatx4 bv = *(floatx4*)&wgl[192 + 4*jc];     // bR,bZ,bNi,bNh in one b128
      // hprev prefetch: issue LDS reads before the MFMA cluster so their
      // latency hides under the 24 MFMAs instead of the epilogue chain.
      unsigned hpw[4];
      #pragma unroll
      for (int r = 0; r < 4; ++r)
        hpw[r] = hwp[(quad*4 + r)*HSTR2 + (c4<<4) + n16];
      floatx4 aR = (floatx4){bv[0], bv[0], bv[0], bv[0]};
      floatx4 aZ = (floatx4){bv[1], bv[1], bv[1], bv[1]};
      floatx4 aN = (floatx4){bv[2], bv[2], bv[2], bv[2]};
      floatx4 aH = (floatx4){bv[3], bv[3], bv[3], bv[3]};
      #pragma unroll
      for (int kt = 0; kt < 4; ++kt){
        int qr = (c4<<2) + kt;
        half8 wR = *(const half8*)&Bl[qr*512 + lane*8];
        aR = __builtin_amdgcn_mfma_f32_16x16x32_f16(ahi[kt], wR, aR, 0,0,0);
        aR = __builtin_amdgcn_mfma_f32_16x16x32_f16(alo[kt], wR, aR, 0,0,0);
        int qz = 16 + (c4<<2) + kt;
        half8 wZ = *(const half8*)&Bl[qz*512 + lane*8];
        aZ = __builtin_amdgcn_mfma_f32_16x16x32_f16(ahi[kt], wZ, aZ, 0,0,0);
        aZ = __builtin_amdgcn_mfma_f32_16x16x32_f16(alo[kt], wZ, aZ, 0,0,0);
        if (kt < 2){
          int qn = 32 + (c4<<1) + kt;
          half8 wN = *(const half8*)&Bl[qn*512 + lane*8];
          aN = __builtin_amdgcn_mfma_f32_16x16x32_f16(ahi[kt], wN, aN, 0,0,0);
          aN = __builtin_amdgcn_mfma_f32_16x16x32_f16(alo[kt], wN, aN, 0,0,0);
        } else {
          int qh = 40 + (c4<<1) + (kt-2);
          half8 wH = *(const half8*)&Bl[qh*512 + lane*8];
          aH = __builtin_amdgcn_mfma_f32_16x16x32_f16(ahi[kt], wH, aH, 0,0,0);
          aH = __builtin_amdgcn_mfma_f32_16x16x32_f16(alo[kt], wH, aH, 0,0,0);
        }
      }
      // epilogue: C/D row = quad*4+r, col = c4*16+n16
      #pragma unroll
      for (int r = 0; r < 4; ++r){
        fp16x2 hp2 = __builtin_bit_cast(fp16x2, hpw[r]);
        float hprev = (float)hp2[0] + (float)hp2[1];
        float rg = fast_sigmoid(aR[r]);
        float zg = fast_sigmoid(aZ[r]);
        float ng = fast_tanh(fmaf(rg, aH[r], aN[r]));
        float hn = fmaf(zg, hprev - ng, ng);
        fp16x2 t0 = __builtin_amdgcn_cvt_pkrtz(hn, hn);
        float back = (float)t0[0];
        fp16x2 pw = __builtin_amdgcn_cvt_pkrtz(hn, hn - back);
        hwp[(quad*4 + r)*HSTR2 + (c4<<4) + n16] = __builtin_bit_cast(unsigned, pw);
      }
    }
    rcur = rnx;
  }

  // FC epilogue: reconstruct h = hi + lo
  #pragma unroll 1
  for (int m = 0; m < 16; ++m){
    fp16x2 hw2 = __builtin_bit_cast(fp16x2, hwp[m*HSTR2 + lane]);
    float hv = (float)hw2[0] + (float)hw2[1];
    float v = hv * wfc;
    #pragma unroll
    for (int off = 32; off >= 1; off >>= 1) v += __shfl_xor(v, off, 64);
    int n = n0 + m;
    if (lane == 0 && n < N) out[n] = v + bfc;
  }
}

extern "C" void kernel_launch(void* const* d_in, const int* in_sizes, int n_in,
                              void* d_out, int out_size, void* d_ws, size_t ws_size,
                              hipStream_t stream){
  const float* x     = (const float*)d_in[0];
  const int*   ei    = (const int*)d_in[1];
  const float* W_gcn = (const float*)d_in[2];
  const float* b_gcn = (const float*)d_in[3];
  const float* W_ih  = (const float*)d_in[4];
  const float* W_hh  = (const float*)d_in[5];
  const float* b_ih  = (const float*)d_in[6];
  const float* b_hh  = (const float*)d_in[7];
  const float* W_fc  = (const float*)d_in[8];
  const float* b_fc  = (const float*)d_in[9];
  float* out = (float*)d_out;
  const int N = in_sizes[0] / (T_STEPS*2);
  const int E = in_sizes[1] / 2;
  const int NB1024 = (N + 1023) / 1024;

  char* p = (char*)d_ws;
  auto alloc = [&](size_t bytes)->char*{
    char* r = p; p += (bytes + 255) & ~(size_t)255; return r;
  };
  int*   cnt       = (int*)  alloc((size_t)N*4);
  int*   row_start = (int*)  alloc((size_t)(N+1)*4);
  int*   rank      = (int*)  alloc((size_t)E*4);
  int*   csr       = (int*)  alloc((size_t)E*4);
  float* dinv      = (float*)alloc((size_t)N*4);
  int*   part      = (int*)  alloc((size_t)N*4);
  int*   bsum      = (int*)  alloc((size_t)NB1024*4);
  float* rin       = (float*)alloc((size_t)N*24*4);
  float* xs        = (float*)alloc((size_t)N*24*4);
  unsigned short* Bpk = (unsigned short*)alloc((size_t)24576*2);

  hipMemsetAsync(cnt, 0, (size_t)N*4, stream);
  {
    int work = (E > 48*512) ? E : 48*512;
    count_packB_kernel<<<(work+255)/256, 256, 0, stream>>>(ei, E, cnt, rank, W_ih, W_hh, Bpk);
  }
  scan1_kernel<<<NB1024, 1024, 0, stream>>>(cnt, part, bsum, N);
  scan3_kernel<<<(N+255)/256, 256, 0, stream>>>(part, bsum, cnt, row_start,
                                                x, dinv, (float4*)xs, N, NB1024);
  fill_kernel<<<(E+255)/256, 256, 0, stream>>>(ei, E, row_start, rank, csr);
  gather6_kernel<<<(N*6+255)/256, 256, 0, stream>>>((const float4*)xs, row_start, csr,
                                                    dinv, (float4*)rin, N);

  (void)hipFuncSetAttribute((const void*)gru16_kernel,
                            hipFuncAttributeMaxDynamicSharedMemorySize, LDS_TOTAL);
  int ntiles = (N + 15) / 16;                      // 3125
  int blocks = (ntiles + GWPB - 1) / GWPB;         // 241
  gru16_kernel<<<blocks, GBLOCK, LDS_TOTAL, stream>>>(rin, W_gcn, b_gcn, Bpk,
                                                      b_ih, b_hh, W_fc, b_fc,
                                                      out, N, ntiles);
}

// Round 8
// 229.420 us; speedup vs baseline: 1.0771x; 1.0427x over previous
//
#include <hip/hip_runtime.h>
#include <hip/hip_fp16.h>
#include <math.h>

#define T_STEPS 12
#define HID 64
#define GWPB 13             // waves per block (241 blocks <= 256 CUs, all resident)
#define GBLOCK (GWPB*64)    // 832 threads
#define HSTR2 68            // h-tile row stride in f32 (64 + 4 pad)
#define B_LDS_BYTES 49152   // 48 slots x 512 fp16 (single-precision-B, fp16)
#define WG_LDS_BYTES 1792   // W_gcn(128) + b_gcn(64) + interleaved biases (256) = 448 f32
#define H_LDS_BYTES (GWPB*16*HSTR2*4)   // 56576
#define LDS_TOTAL (B_LDS_BYTES + WG_LDS_BYTES + H_LDS_BYTES)  // 107520

typedef _Float16 half8 __attribute__((ext_vector_type(8)));
typedef __fp16   fp16x2 __attribute__((ext_vector_type(2)));   // pkrtz result type
typedef __attribute__((ext_vector_type(4))) float floatx4;

// Fast transcendentals: without -ffast-math, 1.0f/x lowers to the full IEEE
// divide sequence (~10 serially-dependent VALU ops). v_rcp_f32 is ~1ulp.
__device__ __forceinline__ float fast_sigmoid(float x){
  float e = __builtin_amdgcn_exp2f(-1.442695041f * x);
  return __builtin_amdgcn_rcpf(1.0f + e);
}
__device__ __forceinline__ float fast_tanh(float x){   // tanh(x) = 1 - 2/(1+e^{2x})
  float e = __builtin_amdgcn_exp2f(2.885390082f * x);
  return fmaf(-2.0f, __builtin_amdgcn_rcpf(1.0f + e), 1.0f);
}
// split f32 pair -> fp16 hi pair + fp16 residual pair (RTZ hi, residual near-exact)
__device__ __forceinline__ void split2(float f0, float f1, unsigned &hi, unsigned &lo){
  fp16x2 h = __builtin_amdgcn_cvt_pkrtz(f0, f1);
  float b0 = (float)h[0], b1 = (float)h[1];
  fp16x2 l = __builtin_amdgcn_cvt_pkrtz(f0 - b0, f1 - b1);
  hi = __builtin_bit_cast(unsigned, h);
  lo = __builtin_bit_cast(unsigned, l);
}

// --- CSR build ----------------------------------------------------------
// count + rank + packB fused. The atomicAdd RETURN VALUE is the per-dst
// sequence number — storing it lets fill_kernel run with ZERO atomics.
__global__ void count_packB_kernel(const int* __restrict__ ei, int E, int* __restrict__ cnt,
                                   int* __restrict__ rank,
                                   const float* __restrict__ W_ih, const float* __restrict__ W_hh,
                                   unsigned short* __restrict__ Bpk){
  int tid = blockIdx.x*blockDim.x + threadIdx.x;
  if (tid < E) rank[tid] = atomicAdd(&cnt[ei[E + tid]], 1);
  if (tid < 48*512){
    int q = tid >> 9;
    int rr = tid & 511;
    int l = rr >> 3, j = rr & 7;
    int g, c4, kt;
    if (q < 32){ g = q >> 4; int rem = q & 15; c4 = rem >> 2; kt = rem & 3; }
    else if (q < 40){ g = 2; c4 = (q-32) >> 1; kt = (q-32) & 1; }
    else            { g = 3; c4 = (q-40) >> 1; kt = ((q-40) & 1) + 2; }
    int k  = kt*32 + (l >> 4)*8 + j;
    int n  = l & 15;
    int jc = c4*16 + n;
    float w;
    if (g == 0)      w = (k < 64) ? W_ih[jc*64 + k]      : W_hh[jc*64 + (k-64)];
    else if (g == 1) w = (k < 64) ? W_ih[(64+jc)*64 + k] : W_hh[(64+jc)*64 + (k-64)];
    else if (g == 2) w = W_ih[(128+jc)*64 + k];
    else             w = W_hh[(128+jc)*64 + (k-64)];
    _Float16 hv = (_Float16)w;   // RNE
    Bpk[q*512 + l*8 + j] = __builtin_bit_cast(unsigned short, hv);
  }
}

// per-1024-block inclusive scan: wave shfl-scan + cross-wave fixup (2 barriers)
__global__ void scan1_kernel(const int* __restrict__ cnt, int* __restrict__ part,
                             int* __restrict__ bsum, int N){
  __shared__ int wsum[16];
  int tid = threadIdx.x;
  int g = blockIdx.x*1024 + tid;
  int v = (g < N) ? cnt[g] : 0;
  int lane = tid & 63, wv = tid >> 6;
  int s = v;
  #pragma unroll
  for (int off = 1; off < 64; off <<= 1){
    int u = __shfl_up(s, off, 64);
    if (lane >= off) s += u;
  }
  if (lane == 63) wsum[wv] = s;
  __syncthreads();
  if (wv == 0){
    int w = (lane < 16) ? wsum[lane] : 0;
    #pragma unroll
    for (int off = 1; off < 16; off <<= 1){
      int u = __shfl_up(w, off, 64);
      if (lane >= off) w += u;
    }
    if (lane < 16) wsum[lane] = w;
  }
  __syncthreads();
  int incl = (wv ? wsum[wv-1] : 0) + s;
  if (g < N) part[g] = incl;
  if (tid == 1023) bsum[blockIdx.x] = incl;
}

// scan3 with scan2 inlined + dinv_scale fused (scan3 already reads cnt[g]
// per node; adding the dinv/xs writes here deletes a dispatch + a cnt pass).
__global__ void scan3_kernel(const int* __restrict__ part, const int* __restrict__ bsum,
                             const int* __restrict__ cnt, int* __restrict__ row_start,
                             const float* __restrict__ x, float* __restrict__ dinv,
                             float4* __restrict__ xs, int N, int nb){
  __shared__ int sb[64];
  if (threadIdx.x < 64){
    int v = (threadIdx.x < nb) ? bsum[threadIdx.x] : 0;
    #pragma unroll
    for (int off = 1; off < 64; off <<= 1){
      int u = __shfl_up(v, off, 64);
      if ((int)(threadIdx.x & 63) >= off) v += u;
    }
    sb[threadIdx.x] = v;
  }
  __syncthreads();
  int g = blockIdx.x*blockDim.x + threadIdx.x;
  if (g < N){
    int c = cnt[g];
    int b = g >> 10;
    int incl = part[g] + (b ? sb[b-1] : 0);
    row_start[g] = incl - c;
    if (g == N-1) row_start[N] = incl;
    float dn = rsqrtf((float)c + 1.0f);
    dinv[g] = dn;
    const float4* xg = (const float4*)x + (size_t)g*6;
    float4* xo = xs + (size_t)g*6;
    #pragma unroll
    for (int q = 0; q < 6; ++q){
      float4 v4 = xg[q];
      xo[q] = make_float4(dn*v4.x, dn*v4.y, dn*v4.z, dn*v4.w);
    }
  }
}

// atomic-free fill: position = row_start[dst] + rank[e] (rank from count pass)
__global__ void fill_kernel(const int* __restrict__ ei, int E,
                            const int* __restrict__ row_start,
                            const int* __restrict__ rank, int* __restrict__ csr){
  int e = blockIdx.x*blockDim.x + threadIdx.x;
  if (e < E){
    int dst = ei[E + e];
    csr[row_start[dst] + rank[e]] = ei[e];  // src
  }
}

__global__ void gather6_kernel(const float4* __restrict__ xs, const int* __restrict__ row_start,
                               const int* __restrict__ csr, const float* __restrict__ dinv,
                               float4* __restrict__ rin, int N){
  int tid = blockIdx.x*blockDim.x + threadIdx.x;
  if (tid >= N*6) return;
  int n = tid / 6;
  int q = tid - n*6;
  int s0 = row_start[n], s1 = row_start[n+1];
  float4 acc = xs[n*6 + q];          // self term
  int e = s0;
  for (; e + 1 < s1; e += 2){
    int sa = csr[e], sb = csr[e+1];
    float4 va = xs[sa*6 + q];
    float4 vb = xs[sb*6 + q];
    acc.x += va.x + vb.x;
    acc.y += va.y + vb.y;
    acc.z += va.z + vb.z;
    acc.w += va.w + vb.w;
  }
  if (e < s1){
    float4 va = xs[csr[e]*6 + q];
    acc.x += va.x; acc.y += va.y; acc.z += va.z; acc.w += va.w;
  }
  float dn = dinv[n];
  rin[tid] = make_float4(dn*acc.x, dn*acc.y, dn*acc.z, dn*acc.w);
}

// Fused 12-step GRU + FC via fp16 2-term MFMA (Ahi*B + Alo*B; B single fp16).
// Wave-private: wave = 16 nodes, owns all 64 channels, NO barriers in t-loop.
// 13 waves/block, 241 blocks (proven config; 7-wave/32-node regressed, wgl
// hoist regressed — kernel is dependency-stall bound, keep the scheduler fed).
// THIS ROUND: h-tile stores plain f32 instead of packed fp16 hi|lo. Removes
// 7 VALU/element of precision plumbing (hprev recon + hn re-pack) from the
// SERIAL epilogue chain; fragment build does split2 from f32 instead of prm
// unpack (+24 VALU/t-step in an MFMA-overlapped phase). LDS bytes, read/write
// counts, addresses, bank profile identical (u32/elem -> f32/elem). Numerics:
// split values bit-identical; hprev now exact (was 2^-21-approx).
__global__ __attribute__((amdgpu_waves_per_eu(1, 4))) __launch_bounds__(GBLOCK)
void gru16_kernel(const float* __restrict__ rin,
                  const float* __restrict__ W_gcn, const float* __restrict__ b_gcn,
                  const unsigned short* __restrict__ Bpk,
                  const float* __restrict__ b_ih, const float* __restrict__ b_hh,
                  const float* __restrict__ W_fc, const float* __restrict__ b_fc,
                  float* __restrict__ out, int N, int ntiles){
  extern __shared__ char smem[];
  unsigned short* Bl = (unsigned short*)smem;
  float*    wgl = (float*)(smem + B_LDS_BYTES);
  float*    hl  = (float*)(smem + B_LDS_BYTES + WG_LDS_BYTES);

  {
    const int4* Bg = (const int4*)Bpk;
    int4* Bd = (int4*)smem;
    for (int i = threadIdx.x; i < 3072; i += GBLOCK) Bd[i] = Bg[i];
    if (threadIdx.x < 64){
      int l = threadIdx.x;
      wgl[l]       = W_gcn[l];
      wgl[64 + l]  = W_gcn[64 + l];
      wgl[128 + l] = b_gcn[l];
      // interleaved per-channel biases: one b128 read per c4 in the hot loop
      wgl[192 + 4*l + 0] = b_ih[l]       + b_hh[l];        // bR
      wgl[192 + 4*l + 1] = b_ih[64 + l]  + b_hh[64 + l];   // bZ
      wgl[192 + 4*l + 2] = b_ih[128 + l];                  // bNi
      wgl[192 + 4*l + 3] = b_hh[128 + l];                  // bNh
    }
  }
  __syncthreads();

  int lane = threadIdx.x & 63;
  int wid  = threadIdx.x >> 6;
  int tile = blockIdx.x*GWPB + wid;
  if (tile >= ntiles) return;
  int n0   = tile << 4;
  int quad = lane >> 4;
  int n16  = lane & 15;
  float* hwp = hl + wid*(16*HSTR2);

  for (int i = lane; i < 16*HSTR2; i += 64) hwp[i] = 0.f;   // wave-private, no barrier

  float wfc = W_fc[lane], bfc = b_fc[0];

  int nn = n0 + n16; if (nn > N-1) nn = N-1;
  const float* rbase = rin + (size_t)nn*24;
  float2 rcur = *(const float2*)rbase;

  #pragma unroll 1
  for (int t = 0; t < T_STEPS; ++t){
    float2 rnx = (t < T_STEPS-1) ? *(const float2*)(rbase + 2*(t+1)) : rcur;

    half8 ahi[4], alo[4];
    // s half (kt 0,1): compute in A-frag layout from wgl, fp16 split
    #pragma unroll
    for (int kt = 0; kt < 2; ++kt){
      int j0 = kt*32 + quad*8;
      floatx4 g0a = *(floatx4*)&wgl[j0],       g0b = *(floatx4*)&wgl[j0+4];
      floatx4 g1a = *(floatx4*)&wgl[64 + j0],  g1b = *(floatx4*)&wgl[64 + j0+4];
      floatx4 bga = *(floatx4*)&wgl[128 + j0], bgb = *(floatx4*)&wgl[128 + j0+4];
      float f[8];
      #pragma unroll
      for (int j = 0; j < 4; ++j){
        f[j]   = fmaxf(fmaf(rcur.x, g0a[j], fmaf(rcur.y, g1a[j], bga[j])), 0.f);
        f[4+j] = fmaxf(fmaf(rcur.x, g0b[j], fmaf(rcur.y, g1b[j], bgb[j])), 0.f);
      }
      union { half8 v; unsigned w[4]; } H, L;
      #pragma unroll
      for (int p2 = 0; p2 < 4; ++p2)
        split2(f[2*p2], f[2*p2+1], H.w[p2], L.w[p2]);
      ahi[kt] = H.v; alo[kt] = L.v;
    }
    // h half (kt 2,3): f32 h from LDS, same split2 as s-half
    #pragma unroll
    for (int kt = 2; kt < 4; ++kt){
      int base = n16*HSTR2 + (kt-2)*32 + quad*8;
      floatx4 fa = *(const floatx4*)&hwp[base];
      floatx4 fb = *(const floatx4*)&hwp[base+4];
      union { half8 v; unsigned w[4]; } H, L;
      split2(fa[0], fa[1], H.w[0], L.w[0]);
      split2(fa[2], fa[3], H.w[1], L.w[1]);
      split2(fb[0], fb[1], H.w[2], L.w[2]);
      split2(fb[2], fb[3], H.w[3], L.w[3]);
      ahi[kt] = H.v; alo[kt] = L.v;
    }

    // unroll-2: two gate-groups in flight (epilogue ∥ next LDS/MFMA).
    #pragma unroll 2
    for (int c4 = 0; c4 < 4; ++c4){
      int jc = (c4<<4) + n16;
      floatx4 bv = *(floatx4*)&wgl[192 + 4*jc];     // bR,bZ,bNi,bNh in one b128
      // hprev prefetch: issue LDS reads before the MFMA cluster so their
      // latency hides under the 24 MFMAs instead of the epilogue chain.
      float hpw[4];
      #pragma unroll
      for (int r = 0; r < 4; ++r)
        hpw[r] = hwp[(quad*4 + r)*HSTR2 + (c4<<4) + n16];
      floatx4 aR = (floatx4){bv[0], bv[0], bv[0], bv[0]};
      floatx4 aZ = (floatx4){bv[1], bv[1], bv[1], bv[1]};
      floatx4 aN = (floatx4){bv[2], bv[2], bv[2], bv[2]};
      floatx4 aH = (floatx4){bv[3], bv[3], bv[3], bv[3]};
      #pragma unroll
      for (int kt = 0; kt < 4; ++kt){
        int qr = (c4<<2) + kt;
        half8 wR = *(const half8*)&Bl[qr*512 + lane*8];
        aR = __builtin_amdgcn_mfma_f32_16x16x32_f16(ahi[kt], wR, aR, 0,0,0);
        aR = __builtin_amdgcn_mfma_f32_16x16x32_f16(alo[kt], wR, aR, 0,0,0);
        int qz = 16 + (c4<<2) + kt;
        half8 wZ = *(const half8*)&Bl[qz*512 + lane*8];
        aZ = __builtin_amdgcn_mfma_f32_16x16x32_f16(ahi[kt], wZ, aZ, 0,0,0);
        aZ = __builtin_amdgcn_mfma_f32_16x16x32_f16(alo[kt], wZ, aZ, 0,0,0);
        if (kt < 2){
          int qn = 32 + (c4<<1) + kt;
          half8 wN = *(const half8*)&Bl[qn*512 + lane*8];
          aN = __builtin_amdgcn_mfma_f32_16x16x32_f16(ahi[kt], wN, aN, 0,0,0);
          aN = __builtin_amdgcn_mfma_f32_16x16x32_f16(alo[kt], wN, aN, 0,0,0);
        } else {
          int qh = 40 + (c4<<1) + (kt-2);
          half8 wH = *(const half8*)&Bl[qh*512 + lane*8];
          aH = __builtin_amdgcn_mfma_f32_16x16x32_f16(ahi[kt], wH, aH, 0,0,0);
          aH = __builtin_amdgcn_mfma_f32_16x16x32_f16(alo[kt], wH, aH, 0,0,0);
        }
      }
      // epilogue: C/D row = quad*4+r, col = c4*16+n16; h stored as plain f32
      #pragma unroll
      for (int r = 0; r < 4; ++r){
        float hprev = hpw[r];
        float rg = fast_sigmoid(aR[r]);
        float zg = fast_sigmoid(aZ[r]);
        float ng = fast_tanh(fmaf(rg, aH[r], aN[r]));
        float hn = fmaf(zg, hprev - ng, ng);
        hwp[(quad*4 + r)*HSTR2 + (c4<<4) + n16] = hn;
      }
    }
    rcur = rnx;
  }

  // FC epilogue: h already f32
  #pragma unroll 1
  for (int m = 0; m < 16; ++m){
    float hv = hwp[m*HSTR2 + lane];
    float v = hv * wfc;
    #pragma unroll
    for (int off = 32; off >= 1; off >>= 1) v += __shfl_xor(v, off, 64);
    int n = n0 + m;
    if (lane == 0 && n < N) out[n] = v + bfc;
  }
}

extern "C" void kernel_launch(void* const* d_in, const int* in_sizes, int n_in,
                              void* d_out, int out_size, void* d_ws, size_t ws_size,
                              hipStream_t stream){
  const float* x     = (const float*)d_in[0];
  const int*   ei    = (const int*)d_in[1];
  const float* W_gcn = (const float*)d_in[2];
  const float* b_gcn = (const float*)d_in[3];
  const float* W_ih  = (const float*)d_in[4];
  const float* W_hh  = (const float*)d_in[5];
  const float* b_ih  = (const float*)d_in[6];
  const float* b_hh  = (const float*)d_in[7];
  const float* W_fc  = (const float*)d_in[8];
  const float* b_fc  = (const float*)d_in[9];
  float* out = (float*)d_out;
  const int N = in_sizes[0] / (T_STEPS*2);
  const int E = in_sizes[1] / 2;
  const int NB1024 = (N + 1023) / 1024;

  char* p = (char*)d_ws;
  auto alloc = [&](size_t bytes)->char*{
    char* r = p; p += (bytes + 255) & ~(size_t)255; return r;
  };
  int*   cnt       = (int*)  alloc((size_t)N*4);
  int*   row_start = (int*)  alloc((size_t)(N+1)*4);
  int*   rank      = (int*)  alloc((size_t)E*4);
  int*   csr       = (int*)  alloc((size_t)E*4);
  float* dinv      = (float*)alloc((size_t)N*4);
  int*   part      = (int*)  alloc((size_t)N*4);
  int*   bsum      = (int*)  alloc((size_t)NB1024*4);
  float* rin       = (float*)alloc((size_t)N*24*4);
  float* xs        = (float*)alloc((size_t)N*24*4);
  unsigned short* Bpk = (unsigned short*)alloc((size_t)24576*2);

  hipMemsetAsync(cnt, 0, (size_t)N*4, stream);
  {
    int work = (E > 48*512) ? E : 48*512;
    count_packB_kernel<<<(work+255)/256, 256, 0, stream>>>(ei, E, cnt, rank, W_ih, W_hh, Bpk);
  }
  scan1_kernel<<<NB1024, 1024, 0, stream>>>(cnt, part, bsum, N);
  scan3_kernel<<<(N+255)/256, 256, 0, stream>>>(part, bsum, cnt, row_start,
                                                x, dinv, (float4*)xs, N, NB1024);
  fill_kernel<<<(E+255)/256, 256, 0, stream>>>(ei, E, row_start, rank, csr);
  gather6_kernel<<<(N*6+255)/256, 256, 0, stream>>>((const float4*)xs, row_start, csr,
                                                    dinv, (float4*)rin, N);

  (void)hipFuncSetAttribute((const void*)gru16_kernel,
                            hipFuncAttributeMaxDynamicSharedMemorySize, LDS_TOTAL);
  int ntiles = (N + 15) / 16;                      // 3125
  int blocks = (ntiles + GWPB - 1) / GWPB;         // 241
  gru16_kernel<<<blocks, GBLOCK, LDS_TOTAL, stream>>>(rin, W_gcn, b_gcn, Bpk,
                                                      b_ih, b_hh, W_fc, b_fc,
                                                      out, N, ntiles);
}

// Round 9
// 227.278 us; speedup vs baseline: 1.0873x; 1.0094x over previous
//
#include <hip/hip_runtime.h>
#include <hip/hip_fp16.h>
#include <math.h>

#define T_STEPS 12
#define HID 64
#define GWPB 13             // waves per block (241 blocks <= 256 CUs, all resident)
#define GBLOCK (GWPB*64)    // 832 threads
#define HSTR2 68            // h-tile row stride in f32 (64 + 4 pad)
#define B_LDS_BYTES 49152   // 48 slots x 512 fp16 (single-precision-B, fp16)
#define WG_LDS_BYTES 1792   // W_gcn(128) + b_gcn(64) + interleaved biases (256) = 448 f32
#define H_LDS_BYTES (GWPB*16*HSTR2*4)   // 56576
#define LDS_TOTAL (B_LDS_BYTES + WG_LDS_BYTES + H_LDS_BYTES)  // 107520

typedef _Float16 half8 __attribute__((ext_vector_type(8)));
typedef __fp16   fp16x2 __attribute__((ext_vector_type(2)));   // pkrtz result type
typedef __attribute__((ext_vector_type(4))) float floatx4;

// Fast transcendentals: without -ffast-math, 1.0f/x lowers to the full IEEE
// divide sequence (~10 serially-dependent VALU ops). v_rcp_f32 is ~1ulp.
__device__ __forceinline__ float fast_sigmoid(float x){
  float e = __builtin_amdgcn_exp2f(-1.442695041f * x);
  return __builtin_amdgcn_rcpf(1.0f + e);
}
__device__ __forceinline__ float fast_tanh(float x){   // tanh(x) = 1 - 2/(1+e^{2x})
  float e = __builtin_amdgcn_exp2f(2.885390082f * x);
  return fmaf(-2.0f, __builtin_amdgcn_rcpf(1.0f + e), 1.0f);
}
// split f32 pair -> fp16 hi pair + fp16 residual pair (RTZ hi, residual near-exact)
__device__ __forceinline__ void split2(float f0, float f1, unsigned &hi, unsigned &lo){
  fp16x2 h = __builtin_amdgcn_cvt_pkrtz(f0, f1);
  float b0 = (float)h[0], b1 = (float)h[1];
  fp16x2 l = __builtin_amdgcn_cvt_pkrtz(f0 - b0, f1 - b1);
  hi = __builtin_bit_cast(unsigned, h);
  lo = __builtin_bit_cast(unsigned, l);
}

// --- CSR build ----------------------------------------------------------
// count + rank + packB fused. The atomicAdd RETURN VALUE is the per-dst
// sequence number — storing it lets fill_kernel run with ZERO atomics.
__global__ void count_packB_kernel(const int* __restrict__ ei, int E, int* __restrict__ cnt,
                                   int* __restrict__ rank,
                                   const float* __restrict__ W_ih, const float* __restrict__ W_hh,
                                   unsigned short* __restrict__ Bpk){
  int tid = blockIdx.x*blockDim.x + threadIdx.x;
  if (tid < E) rank[tid] = atomicAdd(&cnt[ei[E + tid]], 1);
  if (tid < 48*512){
    int q = tid >> 9;
    int rr = tid & 511;
    int l = rr >> 3, j = rr & 7;
    int g, c4, kt;
    if (q < 32){ g = q >> 4; int rem = q & 15; c4 = rem >> 2; kt = rem & 3; }
    else if (q < 40){ g = 2; c4 = (q-32) >> 1; kt = (q-32) & 1; }
    else            { g = 3; c4 = (q-40) >> 1; kt = ((q-40) & 1) + 2; }
    int k  = kt*32 + (l >> 4)*8 + j;
    int n  = l & 15;
    int jc = c4*16 + n;
    float w;
    if (g == 0)      w = (k < 64) ? W_ih[jc*64 + k]      : W_hh[jc*64 + (k-64)];
    else if (g == 1) w = (k < 64) ? W_ih[(64+jc)*64 + k] : W_hh[(64+jc)*64 + (k-64)];
    else if (g == 2) w = W_ih[(128+jc)*64 + k];
    else             w = W_hh[(128+jc)*64 + (k-64)];
    _Float16 hv = (_Float16)w;   // RNE
    Bpk[q*512 + l*8 + j] = __builtin_bit_cast(unsigned short, hv);
  }
}

// per-1024-block inclusive scan: wave shfl-scan + cross-wave fixup (2 barriers)
__global__ void scan1_kernel(const int* __restrict__ cnt, int* __restrict__ part,
                             int* __restrict__ bsum, int N){
  __shared__ int wsum[16];
  int tid = threadIdx.x;
  int g = blockIdx.x*1024 + tid;
  int v = (g < N) ? cnt[g] : 0;
  int lane = tid & 63, wv = tid >> 6;
  int s = v;
  #pragma unroll
  for (int off = 1; off < 64; off <<= 1){
    int u = __shfl_up(s, off, 64);
    if (lane >= off) s += u;
  }
  if (lane == 63) wsum[wv] = s;
  __syncthreads();
  if (wv == 0){
    int w = (lane < 16) ? wsum[lane] : 0;
    #pragma unroll
    for (int off = 1; off < 16; off <<= 1){
      int u = __shfl_up(w, off, 64);
      if (lane >= off) w += u;
    }
    if (lane < 16) wsum[lane] = w;
  }
  __syncthreads();
  int incl = (wv ? wsum[wv-1] : 0) + s;
  if (g < N) part[g] = incl;
  if (tid == 1023) bsum[blockIdx.x] = incl;
}

// scan3 with scan2 inlined + dinv_scale fused (scan3 already reads cnt[g]
// per node; adding the dinv/xs writes here deletes a dispatch + a cnt pass).
__global__ void scan3_kernel(const int* __restrict__ part, const int* __restrict__ bsum,
                             const int* __restrict__ cnt, int* __restrict__ row_start,
                             const float* __restrict__ x, float* __restrict__ dinv,
                             float4* __restrict__ xs, int N, int nb){
  __shared__ int sb[64];
  if (threadIdx.x < 64){
    int v = (threadIdx.x < nb) ? bsum[threadIdx.x] : 0;
    #pragma unroll
    for (int off = 1; off < 64; off <<= 1){
      int u = __shfl_up(v, off, 64);
      if ((int)(threadIdx.x & 63) >= off) v += u;
    }
    sb[threadIdx.x] = v;
  }
  __syncthreads();
  int g = blockIdx.x*blockDim.x + threadIdx.x;
  if (g < N){
    int c = cnt[g];
    int b = g >> 10;
    int incl = part[g] + (b ? sb[b-1] : 0);
    row_start[g] = incl - c;
    if (g == N-1) row_start[N] = incl;
    float dn = rsqrtf((float)c + 1.0f);
    dinv[g] = dn;
    const float4* xg = (const float4*)x + (size_t)g*6;
    float4* xo = xs + (size_t)g*6;
    #pragma unroll
    for (int q = 0; q < 6; ++q){
      float4 v4 = xg[q];
      xo[q] = make_float4(dn*v4.x, dn*v4.y, dn*v4.z, dn*v4.w);
    }
  }
}

// atomic-free fill: position = row_start[dst] + rank[e] (rank from count pass)
__global__ void fill_kernel(const int* __restrict__ ei, int E,
                            const int* __restrict__ row_start,
                            const int* __restrict__ rank, int* __restrict__ csr){
  int e = blockIdx.x*blockDim.x + threadIdx.x;
  if (e < E){
    int dst = ei[E + e];
    csr[row_start[dst] + rank[e]] = ei[e];  // src
  }
}

// Divergence-balanced gather: TWO lanes per (node,quarter), parity-strided
// over the CSR row, combined via shfl_xor(1). A 64-lane wave previously ran
// E[max of ~11 Poisson(16)] ≈ 28 iterations for 16 useful; the 2-way split
// halves the per-thread bound (~12-14) and doubles TLP (9.4 waves/SIMD).
// Total csr/xs load issue unchanged (each thread reads half its row).
__global__ void gather6_kernel(const float4* __restrict__ xs, const int* __restrict__ row_start,
                               const int* __restrict__ csr, const float* __restrict__ dinv,
                               float4* __restrict__ rin, int N){
  int tid = blockIdx.x*blockDim.x + threadIdx.x;
  if (tid >= N*12) return;
  int pq  = tid >> 1;        // (node, quarter) index
  int par = tid & 1;
  int n = pq / 6;
  int q = pq - n*6;
  int s0 = row_start[n], s1 = row_start[n+1];
  float4 acc = make_float4(0.f, 0.f, 0.f, 0.f);
  int e = s0 + par;
  for (; e + 2 < s1; e += 4){
    float4 va = xs[csr[e]*6 + q];
    float4 vb = xs[csr[e+2]*6 + q];
    acc.x += va.x + vb.x;
    acc.y += va.y + vb.y;
    acc.z += va.z + vb.z;
    acc.w += va.w + vb.w;
  }
  if (e < s1){
    float4 va = xs[csr[e]*6 + q];
    acc.x += va.x; acc.y += va.y; acc.z += va.z; acc.w += va.w;
  }
  // combine the parity pair (lanes differ in bit 0)
  acc.x += __shfl_xor(acc.x, 1, 64);
  acc.y += __shfl_xor(acc.y, 1, 64);
  acc.z += __shfl_xor(acc.z, 1, 64);
  acc.w += __shfl_xor(acc.w, 1, 64);
  if (par == 0){
    float4 self = xs[n*6 + q];
    float dn = dinv[n];
    rin[pq] = make_float4(dn*(acc.x + self.x), dn*(acc.y + self.y),
                          dn*(acc.z + self.z), dn*(acc.w + self.w));
  }
}

// Fused 12-step GRU + FC via fp16 2-term MFMA (Ahi*B + Alo*B; B single fp16).
// Wave-private: wave = 16 nodes, owns all 64 channels, NO barriers in t-loop.
// 13 waves/block, 241 blocks (proven config; 7-wave/32-node regressed, wgl
// hoist regressed — kernel is dependency-stall bound, keep the scheduler fed).
// h-tile stores plain f32 (round-8 win: removed serial hi|lo plumbing).
__global__ __attribute__((amdgpu_waves_per_eu(1, 4))) __launch_bounds__(GBLOCK)
void gru16_kernel(const float* __restrict__ rin,
                  const float* __restrict__ W_gcn, const float* __restrict__ b_gcn,
                  const unsigned short* __restrict__ Bpk,
                  const float* __restrict__ b_ih, const float* __restrict__ b_hh,
                  const float* __restrict__ W_fc, const float* __restrict__ b_fc,
                  float* __restrict__ out, int N, int ntiles){
  extern __shared__ char smem[];
  unsigned short* Bl = (unsigned short*)smem;
  float*    wgl = (float*)(smem + B_LDS_BYTES);
  float*    hl  = (float*)(smem + B_LDS_BYTES + WG_LDS_BYTES);

  {
    const int4* Bg = (const int4*)Bpk;
    int4* Bd = (int4*)smem;
    for (int i = threadIdx.x; i < 3072; i += GBLOCK) Bd[i] = Bg[i];
    if (threadIdx.x < 64){
      int l = threadIdx.x;
      wgl[l]       = W_gcn[l];
      wgl[64 + l]  = W_gcn[64 + l];
      wgl[128 + l] = b_gcn[l];
      // interleaved per-channel biases: one b128 read per c4 in the hot loop
      wgl[192 + 4*l + 0] = b_ih[l]       + b_hh[l];        // bR
      wgl[192 + 4*l + 1] = b_ih[64 + l]  + b_hh[64 + l];   // bZ
      wgl[192 + 4*l + 2] = b_ih[128 + l];                  // bNi
      wgl[192 + 4*l + 3] = b_hh[128 + l];                  // bNh
    }
  }
  __syncthreads();

  int lane = threadIdx.x & 63;
  int wid  = threadIdx.x >> 6;
  int tile = blockIdx.x*GWPB + wid;
  if (tile >= ntiles) return;
  int n0   = tile << 4;
  int quad = lane >> 4;
  int n16  = lane & 15;
  float* hwp = hl + wid*(16*HSTR2);

  for (int i = lane; i < 16*HSTR2; i += 64) hwp[i] = 0.f;   // wave-private, no barrier

  float wfc = W_fc[lane], bfc = b_fc[0];

  int nn = n0 + n16; if (nn > N-1) nn = N-1;
  const float* rbase = rin + (size_t)nn*24;
  float2 rcur = *(const float2*)rbase;

  #pragma unroll 1
  for (int t = 0; t < T_STEPS; ++t){
    float2 rnx = (t < T_STEPS-1) ? *(const float2*)(rbase + 2*(t+1)) : rcur;

    half8 ahi[4], alo[4];
    // s half (kt 0,1): compute in A-frag layout from wgl, fp16 split
    #pragma unroll
    for (int kt = 0; kt < 2; ++kt){
      int j0 = kt*32 + quad*8;
      floatx4 g0a = *(floatx4*)&wgl[j0],       g0b = *(floatx4*)&wgl[j0+4];
      floatx4 g1a = *(floatx4*)&wgl[64 + j0],  g1b = *(floatx4*)&wgl[64 + j0+4];
      floatx4 bga = *(floatx4*)&wgl[128 + j0], bgb = *(floatx4*)&wgl[128 + j0+4];
      float f[8];
      #pragma unroll
      for (int j = 0; j < 4; ++j){
        f[j]   = fmaxf(fmaf(rcur.x, g0a[j], fmaf(rcur.y, g1a[j], bga[j])), 0.f);
        f[4+j] = fmaxf(fmaf(rcur.x, g0b[j], fmaf(rcur.y, g1b[j], bgb[j])), 0.f);
      }
      union { half8 v; unsigned w[4]; } H, L;
      #pragma unroll
      for (int p2 = 0; p2 < 4; ++p2)
        split2(f[2*p2], f[2*p2+1], H.w[p2], L.w[p2]);
      ahi[kt] = H.v; alo[kt] = L.v;
    }
    // h half (kt 2,3): f32 h from LDS, same split2 as s-half
    #pragma unroll
    for (int kt = 2; kt < 4; ++kt){
      int base = n16*HSTR2 + (kt-2)*32 + quad*8;
      floatx4 fa = *(const floatx4*)&hwp[base];
      floatx4 fb = *(const floatx4*)&hwp[base+4];
      union { half8 v; unsigned w[4]; } H, L;
      split2(fa[0], fa[1], H.w[0], L.w[0]);
      split2(fa[2], fa[3], H.w[1], L.w[1]);
      split2(fb[0], fb[1], H.w[2], L.w[2]);
      split2(fb[2], fb[3], H.w[3], L.w[3]);
      ahi[kt] = H.v; alo[kt] = L.v;
    }

    // unroll-2: two gate-groups in flight (epilogue ∥ next LDS/MFMA).
    #pragma unroll 2
    for (int c4 = 0; c4 < 4; ++c4){
      int jc = (c4<<4) + n16;
      floatx4 bv = *(floatx4*)&wgl[192 + 4*jc];     // bR,bZ,bNi,bNh in one b128
      // hprev prefetch: issue LDS reads before the MFMA cluster so their
      // latency hides under the 24 MFMAs instead of the epilogue chain.
      float hpw[4];
      #pragma unroll
      for (int r = 0; r < 4; ++r)
        hpw[r] = hwp[(quad*4 + r)*HSTR2 + (c4<<4) + n16];
      floatx4 aR = (floatx4){bv[0], bv[0], bv[0], bv[0]};
      floatx4 aZ = (floatx4){bv[1], bv[1], bv[1], bv[1]};
      floatx4 aN = (floatx4){bv[2], bv[2], bv[2], bv[2]};
      floatx4 aH = (floatx4){bv[3], bv[3], bv[3], bv[3]};
      #pragma unroll
      for (int kt = 0; kt < 4; ++kt){
        int qr = (c4<<2) + kt;
        half8 wR = *(const half8*)&Bl[qr*512 + lane*8];
        aR = __builtin_amdgcn_mfma_f32_16x16x32_f16(ahi[kt], wR, aR, 0,0,0);
        aR = __builtin_amdgcn_mfma_f32_16x16x32_f16(alo[kt], wR, aR, 0,0,0);
        int qz = 16 + (c4<<2) + kt;
        half8 wZ = *(const half8*)&Bl[qz*512 + lane*8];
        aZ = __builtin_amdgcn_mfma_f32_16x16x32_f16(ahi[kt], wZ, aZ, 0,0,0);
        aZ = __builtin_amdgcn_mfma_f32_16x16x32_f16(alo[kt], wZ, aZ, 0,0,0);
        if (kt < 2){
          int qn = 32 + (c4<<1) + kt;
          half8 wN = *(const half8*)&Bl[qn*512 + lane*8];
          aN = __builtin_amdgcn_mfma_f32_16x16x32_f16(ahi[kt], wN, aN, 0,0,0);
          aN = __builtin_amdgcn_mfma_f32_16x16x32_f16(alo[kt], wN, aN, 0,0,0);
        } else {
          int qh = 40 + (c4<<1) + (kt-2);
          half8 wH = *(const half8*)&Bl[qh*512 + lane*8];
          aH = __builtin_amdgcn_mfma_f32_16x16x32_f16(ahi[kt], wH, aH, 0,0,0);
          aH = __builtin_amdgcn_mfma_f32_16x16x32_f16(alo[kt], wH, aH, 0,0,0);
        }
      }
      // epilogue: C/D row = quad*4+r, col = c4*16+n16; h stored as plain f32
      #pragma unroll
      for (int r = 0; r < 4; ++r){
        float hprev = hpw[r];
        float rg = fast_sigmoid(aR[r]);
        float zg = fast_sigmoid(aZ[r]);
        float ng = fast_tanh(fmaf(rg, aH[r], aN[r]));
        float hn = fmaf(zg, hprev - ng, ng);
        hwp[(quad*4 + r)*HSTR2 + (c4<<4) + n16] = hn;
      }
    }
    rcur = rnx;
  }

  // FC epilogue: h already f32
  #pragma unroll 1
  for (int m = 0; m < 16; ++m){
    float hv = hwp[m*HSTR2 + lane];
    float v = hv * wfc;
    #pragma unroll
    for (int off = 32; off >= 1; off >>= 1) v += __shfl_xor(v, off, 64);
    int n = n0 + m;
    if (lane == 0 && n < N) out[n] = v + bfc;
  }
}

extern "C" void kernel_launch(void* const* d_in, const int* in_sizes, int n_in,
                              void* d_out, int out_size, void* d_ws, size_t ws_size,
                              hipStream_t stream){
  const float* x     = (const float*)d_in[0];
  const int*   ei    = (const int*)d_in[1];
  const float* W_gcn = (const float*)d_in[2];
  const float* b_gcn = (const float*)d_in[3];
  const float* W_ih  = (const float*)d_in[4];
  const float* W_hh  = (const float*)d_in[5];
  const float* b_ih  = (const float*)d_in[6];
  const float* b_hh  = (const float*)d_in[7];
  const float* W_fc  = (const float*)d_in[8];
  const float* b_fc  = (const float*)d_in[9];
  float* out = (float*)d_out;
  const int N = in_sizes[0] / (T_STEPS*2);
  const int E = in_sizes[1] / 2;
  const int NB1024 = (N + 1023) / 1024;

  char* p = (char*)d_ws;
  auto alloc = [&](size_t bytes)->char*{
    char* r = p; p += (bytes + 255) & ~(size_t)255; return r;
  };
  int*   cnt       = (int*)  alloc((size_t)N*4);
  int*   row_start = (int*)  alloc((size_t)(N+1)*4);
  int*   rank      = (int*)  alloc((size_t)E*4);
  int*   csr       = (int*)  alloc((size_t)E*4);
  float* dinv      = (float*)alloc((size_t)N*4);
  int*   part      = (int*)  alloc((size_t)N*4);
  int*   bsum      = (int*)  alloc((size_t)NB1024*4);
  float* rin       = (float*)alloc((size_t)N*24*4);
  float* xs        = (float*)alloc((size_t)N*24*4);
  unsigned short* Bpk = (unsigned short*)alloc((size_t)24576*2);

  hipMemsetAsync(cnt, 0, (size_t)N*4, stream);
  {
    int work = (E > 48*512) ? E : 48*512;
    count_packB_kernel<<<(work+255)/256, 256, 0, stream>>>(ei, E, cnt, rank, W_ih, W_hh, Bpk);
  }
  scan1_kernel<<<NB1024, 1024, 0, stream>>>(cnt, part, bsum, N);
  scan3_kernel<<<(N+255)/256, 256, 0, stream>>>(part, bsum, cnt, row_start,
                                                x, dinv, (float4*)xs, N, NB1024);
  fill_kernel<<<(E+255)/256, 256, 0, stream>>>(ei, E, row_start, rank, csr);
  gather6_kernel<<<(N*12+255)/256, 256, 0, stream>>>((const float4*)xs, row_start, csr,
                                                     dinv, (float4*)rin, N);

  (void)hipFuncSetAttribute((const void*)gru16_kernel,
                            hipFuncAttributeMaxDynamicSharedMemorySize, LDS_TOTAL);
  int ntiles = (N + 15) / 16;                      // 3125
  int blocks = (ntiles + GWPB - 1) / GWPB;         // 241
  gru16_kernel<<<blocks, GBLOCK, LDS_TOTAL, stream>>>(rin, W_gcn, b_gcn, Bpk,
                                                      b_ih, b_hh, W_fc, b_fc,
                                                      out, N, ntiles);
}